// Round 7
// baseline (441.098 us; speedup 1.0000x reference)
//
#include <hip/hip_runtime.h>
#include <math.h>

typedef float f4 __attribute__((ext_vector_type(4)));
typedef int   i4 __attribute__((ext_vector_type(4)));

// Problem constants (match reference)
#define Nn     32
#define Ll     2048
#define Cc     256
#define DEMd   8
#define H1d    40
#define H2d    20
#define OUTC   (3 * Cc + H2d)   // 788
#define CHUNKS 128
#define CLEN   (Ll / CHUNKS)    // 16
#define CPT    4                // channels per thread
#define TPB    (Cc / CPT)       // 64 threads = 1 wave per block

// ---------------------------------------------------------------------------
// Wave64 sum via DPP row ops: 6 dependent VALU adds, result broadcast from
// lane 63 via readlane (SALU). No LDS traffic.
// ---------------------------------------------------------------------------
#define DPP_ADD(x, ctrl, rm)                                                   \
    x += __builtin_bit_cast(float, __builtin_amdgcn_update_dpp(                \
             0, __builtin_bit_cast(int, x), ctrl, rm, 0xf, false))

__device__ __forceinline__ float wave_sum(float x)
{
    DPP_ADD(x, 0x111, 0xf);   // row_shr:1
    DPP_ADD(x, 0x112, 0xf);   // row_shr:2
    DPP_ADD(x, 0x114, 0xf);   // row_shr:4
    DPP_ADD(x, 0x118, 0xf);   // row_shr:8
    DPP_ADD(x, 0x142, 0xa);   // row_bcast:15 -> rows 1,3
    DPP_ADD(x, 0x143, 0xc);   // row_bcast:31 -> rows 2,3
    return __builtin_bit_cast(float,
        __builtin_amdgcn_readlane(__builtin_bit_cast(int, x), 63));
}

// ---------------------------------------------------------------------------
// Kernel 1: per-(n, chunk) local scan aggregates, 4 channels/thread.
// Grid: N*CHUNKS blocks x 64 threads. All loads/stores are dwordx4.
// ---------------------------------------------------------------------------
__global__ __launch_bounds__(TPB) void chunk_agg_kernel(
    const float* __restrict__ x,
    float* __restrict__ aggM, int* __restrict__ aggI, float* __restrict__ aggS)
{
    const int bid = blockIdx.x;
    const int n  = bid / CHUNKS;
    const int ch = bid % CHUNKS;
    const int c4 = threadIdx.x * CPT;

    const float* xp = x + ((size_t)(n * Ll + ch * CLEN)) * Cc + c4;

    f4 m = {-INFINITY, -INFINITY, -INFINITY, -INFINITY};
    i4 mi = {0, 0, 0, 0};
    f4 s = {0.f, 0.f, 0.f, 0.f};

    #pragma unroll
    for (int tl = 0; tl < CLEN; ++tl) {
        const f4 v = *reinterpret_cast<const f4*>(xp + (size_t)tl * Cc);
        const int t = ch * CLEN + tl;
        #pragma unroll
        for (int k = 0; k < CPT; ++k) {
            if (v[k] > m[k]) { m[k] = v[k]; mi[k] = t; }   // strict >: first wins
            s[k] += v[k];
        }
    }
    const int o = (n * CHUNKS + ch) * Cc + c4;
    *reinterpret_cast<f4*>(aggM + o) = m;
    *reinterpret_cast<i4*>(aggI + o) = mi;
    *reinterpret_cast<f4*>(aggS + o) = s;
}

// ---------------------------------------------------------------------------
// Kernel 2: in-place exclusive prefix combine over chunks, per (n, c) lane.
// After this, agg*[(n*CHUNKS+ch)*Cc+c] holds the carry ENTERING chunk ch.
// Grid: 128 blocks x 64 threads = 8192 independent (n,c) chains (~24 MB L2).
// ---------------------------------------------------------------------------
__global__ __launch_bounds__(TPB) void prefix_kernel(
    float* __restrict__ aggM, int* __restrict__ aggI, float* __restrict__ aggS)
{
    const int idx = blockIdx.x * TPB + threadIdx.x;   // 0 .. N*Cc-1
    const int n = idx >> 8;
    const int c = idx & (Cc - 1);

    float m = -INFINITY; int mi = 0; float s = 0.f;
    #pragma unroll 4
    for (int j = 0; j < CHUNKS; ++j) {
        const int o = (n * CHUNKS + j) * Cc + c;
        const float am = aggM[o];
        const int   ai = aggI[o];
        const float as = aggS[o];
        aggM[o] = m; aggI[o] = mi; aggS[o] = s;        // exclusive carry
        if (am > m) { m = am; mi = ai; }               // earlier chunk wins ties
        s += as;
    }
}

// ---------------------------------------------------------------------------
// Kernel 3: main fused pass. Block = (n, chunk) = 1 wave, 4 channels/thread.
// 16 timesteps; per step: cummax/cumsum update, pad rule, DPP channel stats
// (two-pass variance), 3 LayerNorms, broadcast-MLP tail, plain dwordx4 stores
// (NT removed this round — suspect under the "kernels are slow" hypothesis).
// ---------------------------------------------------------------------------
__global__ __launch_bounds__(TPB) void pool_ln_kernel(
    const float* __restrict__ x,
    const float* __restrict__ dem,
    const float* __restrict__ lng, const float* __restrict__ lnb,
    const float* __restrict__ w1, const float* __restrict__ b1,
    const float* __restrict__ w2, const float* __restrict__ b2,
    const float* __restrict__ aggM, const int* __restrict__ aggI,
    const float* __restrict__ aggS,
    float* __restrict__ o1, float* __restrict__ o2, float* __restrict__ o3)
{
    __shared__ float h1s[H1d];
    __shared__ __align__(16) float dvec[H2d];

    const int bid  = blockIdx.x;
    const int n    = bid / CHUNKS;
    const int ch   = bid % CHUNKS;
    const int lane = threadIdx.x;          // 0..63
    const int c4   = lane * CPT;

    // --- tiny MLP: d = relu(relu(dem @ w1 + b1) @ w2 + b2), per n ---
    if (lane < H1d) {
        float a = b1[lane];
        #pragma unroll
        for (int k = 0; k < DEMd; ++k) a += dem[n * DEMd + k] * w1[k * H1d + lane];
        h1s[lane] = fmaxf(a, 0.f);
    }
    __syncthreads();
    if (lane < H2d) {
        float a = b2[lane];
        #pragma unroll
        for (int k = 0; k < H1d; ++k) a += h1s[k] * w2[k * H2d + lane];
        dvec[lane] = fmaxf(a, 0.f);
    }
    __syncthreads();
    f4 dvf = {0.f, 0.f, 0.f, 0.f};
    if (lane < H2d / CPT) dvf = *reinterpret_cast<const f4*>(dvec + lane * CPT);

    // --- scan carry for this chunk (exclusive prefix from kernel 2) ---
    const int co = (n * CHUNKS + ch) * Cc + c4;
    f4 m  = *reinterpret_cast<const f4*>(aggM + co);
    i4 mi = *reinterpret_cast<const i4*>(aggI + co);
    f4 s  = *reinterpret_cast<const f4*>(aggS + co);

    // --- LN params for own 4 channels x 3 normalizers ---
    const f4 g0 = *reinterpret_cast<const f4*>(lng + c4);
    const f4 g1 = *reinterpret_cast<const f4*>(lng + Cc + c4);
    const f4 g2 = *reinterpret_cast<const f4*>(lng + 2 * Cc + c4);
    const f4 be0 = *reinterpret_cast<const f4*>(lnb + c4);
    const f4 be1 = *reinterpret_cast<const f4*>(lnb + Cc + c4);
    const f4 be2 = *reinterpret_cast<const f4*>(lnb + 2 * Cc + c4);

    const float invC  = 1.0f / (float)Cc;
    const float invL  = 1.0f / (float)Ll;
    const float invSL = 0.022097086912079612f;   // 1/sqrt(2048)

    const float* xp = x + ((size_t)(n * Ll + ch * CLEN)) * Cc + c4;

    f4 v = *reinterpret_cast<const f4*>(xp);     // prefetch row 0

    for (int tl = 0; tl < CLEN; ++tl) {
        const int t = ch * CLEN + tl;

        // issue next row's load before the dependent reduce chain
        f4 vn;
        if (tl + 1 < CLEN)
            vn = *reinterpret_cast<const f4*>(xp + (size_t)(tl + 1) * Cc);

        f4 pm; f4 pidxf;
        float s0 = 0.f, s2 = 0.f;
        const bool notlast = (t < Ll - 1);
        #pragma unroll
        for (int k = 0; k < CPT; ++k) {
            if (v[k] > m[k]) { m[k] = v[k]; mi[k] = t; }
            s[k] += v[k];
            const bool pad = notlast && (m[k] < 0.f);     // padding zero wins
            const float p  = pad ? 0.f : m[k];
            pm[k]    = p;
            pidxf[k] = pad ? -1.0f : (float)mi[k];
            s0 += p;
            s2 += s[k];
        }

        // pass 1: wave-wide sums of {pm, cs} over all 256 channels (DPP)
        const float muM = wave_sum(s0) * invC;
        const float csm = wave_sum(s2) * invC;

        // pass 2: centered second moments (biased var, matches jnp.var)
        float s1 = 0.f, s3 = 0.f;
        f4 dcs;
        #pragma unroll
        for (int k = 0; k < CPT; ++k) {
            const float dm = pm[k] - muM;
            dcs[k] = s[k] - csm;
            s1 += dm * dm;
            s3 += dcs[k] * dcs[k];
        }
        const float varM  = wave_sum(s1) * invC;
        const float varCS = wave_sum(s3) * invC;

        const float rM = rsqrtf(varM + 1e-5f);
        // shared stats of cumsum serve p_avg (cs/L) and p_sum (cs/sqrt(L))
        const float rA = invL  * rsqrtf(varCS * invL * invL + 1e-5f);
        const float rS = invSL * rsqrtf(varCS * invL + 1e-5f);

        f4 y0, y1, y2;
        #pragma unroll
        for (int k = 0; k < CPT; ++k) {
            y0[k] = (pm[k] - muM) * rM * g0[k] + be0[k];
            y1[k] = dcs[k] * rA * g1[k] + be1[k];
            y2[k] = dcs[k] * rS * g2[k] + be2[k];
        }

        const size_t row = (size_t)(n * Ll + t);
        float* orow = o1 + row * OUTC;
        *reinterpret_cast<f4*>(orow + c4)          = y0;
        *reinterpret_cast<f4*>(orow + Cc + c4)     = y1;
        *reinterpret_cast<f4*>(orow + 2 * Cc + c4) = y2;
        if (lane < H2d / CPT)
            *reinterpret_cast<f4*>(orow + 3 * Cc + lane * CPT) = dvf;
        *reinterpret_cast<f4*>(o2 + row * Cc + c4) = pidxf;
        *reinterpret_cast<f4*>(o3 + row * Cc + c4) = pm;

        v = vn;
    }
}

// ---------------------------------------------------------------------------
extern "C" void kernel_launch(void* const* d_in, const int* in_sizes, int n_in,
                              void* d_out, int out_size, void* d_ws, size_t ws_size,
                              hipStream_t stream)
{
    const float* dem = (const float*)d_in[0];   // (32, 8)
    const float* x   = (const float*)d_in[1];   // (32, 2048, 256)
    const float* lng = (const float*)d_in[2];   // (3, 256)
    const float* lnb = (const float*)d_in[3];   // (3, 256)
    const float* w1  = (const float*)d_in[4];   // (8, 40)
    const float* b1  = (const float*)d_in[5];   // (40,)
    const float* w2  = (const float*)d_in[6];   // (40, 20)
    const float* b2  = (const float*)d_in[7];   // (20,)

    float* out = (float*)d_out;
    float* o1 = out;                                  // (N, L, 788)
    float* o2 = o1 + (size_t)Nn * Ll * OUTC;          // p_max_ind (as float values)
    float* o3 = o2 + (size_t)Nn * Ll * Cc;            // p_max

    // workspace: chunk aggregates (exclusive-prefixed in place by kernel 2)
    const size_t nAgg = (size_t)Nn * CHUNKS * Cc;     // 1048576
    float* aggM = (float*)d_ws;
    int*   aggI = (int*)(aggM + nAgg);
    float* aggS = (float*)(aggI + nAgg);

    chunk_agg_kernel<<<dim3(Nn * CHUNKS), dim3(TPB), 0, stream>>>(x, aggM, aggI, aggS);
    prefix_kernel<<<dim3((Nn * Cc) / TPB), dim3(TPB), 0, stream>>>(aggM, aggI, aggS);
    pool_ln_kernel<<<dim3(Nn * CHUNKS), dim3(TPB), 0, stream>>>(
        x, dem, lng, lnb, w1, b1, w2, b2, aggM, aggI, aggS, o1, o2, o3);
}

// Round 8
// 424.592 us; speedup vs baseline: 1.0389x; 1.0389x over previous
//
#include <hip/hip_runtime.h>
#include <math.h>

typedef float f4 __attribute__((ext_vector_type(4)));
typedef int   i4 __attribute__((ext_vector_type(4)));

// Problem constants (match reference)
#define Nn     32
#define Ll     2048
#define Cc     256
#define DEMd   8
#define H1d    40
#define H2d    20
#define OUTC   (3 * Cc + H2d)   // 788
#define CHUNKS 64
#define CLEN   (Ll / CHUNKS)    // 32
#define CPT    4                // channels per thread
#define TPB    (Cc / CPT)       // 64 threads = 1 wave per block

// ---------------------------------------------------------------------------
// Wave64 sum via DPP row ops: 6 dependent VALU adds, result broadcast from
// lane 63 via readlane (SALU). No LDS traffic.
// ---------------------------------------------------------------------------
#define DPP_ADD(x, ctrl, rm)                                                   \
    x += __builtin_bit_cast(float, __builtin_amdgcn_update_dpp(                \
             0, __builtin_bit_cast(int, x), ctrl, rm, 0xf, false))

__device__ __forceinline__ float wave_sum(float x)
{
    DPP_ADD(x, 0x111, 0xf);   // row_shr:1
    DPP_ADD(x, 0x112, 0xf);   // row_shr:2
    DPP_ADD(x, 0x114, 0xf);   // row_shr:4
    DPP_ADD(x, 0x118, 0xf);   // row_shr:8
    DPP_ADD(x, 0x142, 0xa);   // row_bcast:15 -> rows 1,3
    DPP_ADD(x, 0x143, 0xc);   // row_bcast:31 -> rows 2,3
    return __builtin_bit_cast(float,
        __builtin_amdgcn_readlane(__builtin_bit_cast(int, x), 63));
}

// ---------------------------------------------------------------------------
// Kernel A: per-(n, chunk) local scan aggregates, 4 channels/thread.
// Grid: N*CHUNKS blocks x 64 threads. Plain stores (aggs are re-read by
// kernel B immediately — keep them L2-resident).
// ---------------------------------------------------------------------------
__global__ __launch_bounds__(TPB) void chunk_agg_kernel(
    const float* __restrict__ x,
    float* __restrict__ aggM, int* __restrict__ aggI, float* __restrict__ aggS)
{
    const int bid = blockIdx.x;
    const int n  = bid / CHUNKS;
    const int ch = bid % CHUNKS;
    const int c4 = threadIdx.x * CPT;

    const float* xp = x + ((size_t)(n * Ll + ch * CLEN)) * Cc + c4;

    f4 m = {-INFINITY, -INFINITY, -INFINITY, -INFINITY};
    i4 mi = {0, 0, 0, 0};
    f4 s = {0.f, 0.f, 0.f, 0.f};

    #pragma unroll 4
    for (int tl = 0; tl < CLEN; ++tl) {
        const f4 v = *reinterpret_cast<const f4*>(xp + (size_t)tl * Cc);
        const int t = ch * CLEN + tl;
        #pragma unroll
        for (int k = 0; k < CPT; ++k) {
            if (v[k] > m[k]) { m[k] = v[k]; mi[k] = t; }   // strict >: first wins
            s[k] += v[k];
        }
    }
    const int o = (n * CHUNKS + ch) * Cc + c4;
    *reinterpret_cast<f4*>(aggM + o) = m;
    *reinterpret_cast<i4*>(aggI + o) = mi;
    *reinterpret_cast<f4*>(aggS + o) = s;
}

// ---------------------------------------------------------------------------
// Kernel B: main fused pass. Block = (n, chunk) = 1 wave, 4 channels/thread.
// Carry built by ORDERED lookback over preceding chunk aggs (L2-resident,
// ascending j preserves earliest-index tie semantics). Then 32 timesteps:
// cummax/cumsum update, pad rule, DPP channel stats (two-pass variance),
// 3 LayerNorms, broadcast-MLP tail, NT dwordx4 stores.
// ---------------------------------------------------------------------------
__global__ __launch_bounds__(TPB) void pool_ln_kernel(
    const float* __restrict__ x,
    const float* __restrict__ dem,
    const float* __restrict__ lng, const float* __restrict__ lnb,
    const float* __restrict__ w1, const float* __restrict__ b1,
    const float* __restrict__ w2, const float* __restrict__ b2,
    const float* __restrict__ aggM, const int* __restrict__ aggI,
    const float* __restrict__ aggS,
    float* __restrict__ o1, float* __restrict__ o2, float* __restrict__ o3)
{
    __shared__ float h1s[H1d];
    __shared__ __align__(16) float dvec[H2d];

    const int bid  = blockIdx.x;
    const int n    = bid / CHUNKS;
    const int ch   = bid % CHUNKS;
    const int lane = threadIdx.x;          // 0..63
    const int c4   = lane * CPT;

    // --- tiny MLP: d = relu(relu(dem @ w1 + b1) @ w2 + b2), per n ---
    if (lane < H1d) {
        float a = b1[lane];
        #pragma unroll
        for (int k = 0; k < DEMd; ++k) a += dem[n * DEMd + k] * w1[k * H1d + lane];
        h1s[lane] = fmaxf(a, 0.f);
    }
    __syncthreads();
    if (lane < H2d) {
        float a = b2[lane];
        #pragma unroll
        for (int k = 0; k < H1d; ++k) a += h1s[k] * w2[k * H2d + lane];
        dvec[lane] = fmaxf(a, 0.f);
    }
    __syncthreads();
    f4 dvf = {0.f, 0.f, 0.f, 0.f};
    if (lane < H2d / CPT) dvf = *reinterpret_cast<const f4*>(dvec + lane * CPT);

    // --- carry: ordered lookback over chunks 0..ch-1 (L2-resident aggs) ---
    f4 m = {-INFINITY, -INFINITY, -INFINITY, -INFINITY};
    i4 mi = {0, 0, 0, 0};
    f4 s = {0.f, 0.f, 0.f, 0.f};
    {
        const float* pM = aggM + (size_t)(n * CHUNKS) * Cc + c4;
        const int*   pI = aggI + (size_t)(n * CHUNKS) * Cc + c4;
        const float* pS = aggS + (size_t)(n * CHUNKS) * Cc + c4;
        for (int j = 0; j < ch; ++j) {
            const f4 am = *reinterpret_cast<const f4*>(pM + (size_t)j * Cc);
            const i4 ai = *reinterpret_cast<const i4*>(pI + (size_t)j * Cc);
            const f4 as = *reinterpret_cast<const f4*>(pS + (size_t)j * Cc);
            #pragma unroll
            for (int k = 0; k < CPT; ++k) {
                if (am[k] > m[k]) { m[k] = am[k]; mi[k] = ai[k]; }  // earlier j wins ties
                s[k] += as[k];
            }
        }
    }

    // --- LN params for own 4 channels x 3 normalizers ---
    const f4 g0 = *reinterpret_cast<const f4*>(lng + c4);
    const f4 g1 = *reinterpret_cast<const f4*>(lng + Cc + c4);
    const f4 g2 = *reinterpret_cast<const f4*>(lng + 2 * Cc + c4);
    const f4 be0 = *reinterpret_cast<const f4*>(lnb + c4);
    const f4 be1 = *reinterpret_cast<const f4*>(lnb + Cc + c4);
    const f4 be2 = *reinterpret_cast<const f4*>(lnb + 2 * Cc + c4);

    const float invC  = 1.0f / (float)Cc;
    const float invL  = 1.0f / (float)Ll;
    const float invSL = 0.022097086912079612f;   // 1/sqrt(2048)

    const float* xp = x + ((size_t)(n * Ll + ch * CLEN)) * Cc + c4;

    f4 v = *reinterpret_cast<const f4*>(xp);     // prefetch row 0

    for (int tl = 0; tl < CLEN; ++tl) {
        const int t = ch * CLEN + tl;

        // issue next row's load before the dependent reduce chain
        f4 vn;
        if (tl + 1 < CLEN)
            vn = *reinterpret_cast<const f4*>(xp + (size_t)(tl + 1) * Cc);

        f4 pm; f4 pidxf;
        float s0 = 0.f, s2 = 0.f;
        const bool notlast = (t < Ll - 1);
        #pragma unroll
        for (int k = 0; k < CPT; ++k) {
            if (v[k] > m[k]) { m[k] = v[k]; mi[k] = t; }
            s[k] += v[k];
            const bool pad = notlast && (m[k] < 0.f);     // padding zero wins
            const float p  = pad ? 0.f : m[k];
            pm[k]    = p;
            pidxf[k] = pad ? -1.0f : (float)mi[k];
            s0 += p;
            s2 += s[k];
        }

        // pass 1: wave-wide sums of {pm, cs} over all 256 channels (DPP)
        const float muM = wave_sum(s0) * invC;
        const float csm = wave_sum(s2) * invC;

        // pass 2: centered second moments (biased var, matches jnp.var)
        float s1 = 0.f, s3 = 0.f;
        f4 dcs;
        #pragma unroll
        for (int k = 0; k < CPT; ++k) {
            const float dm = pm[k] - muM;
            dcs[k] = s[k] - csm;
            s1 += dm * dm;
            s3 += dcs[k] * dcs[k];
        }
        const float varM  = wave_sum(s1) * invC;
        const float varCS = wave_sum(s3) * invC;

        const float rM = rsqrtf(varM + 1e-5f);
        // shared stats of cumsum serve p_avg (cs/L) and p_sum (cs/sqrt(L))
        const float rA = invL  * rsqrtf(varCS * invL * invL + 1e-5f);
        const float rS = invSL * rsqrtf(varCS * invL + 1e-5f);

        f4 y0, y1, y2;
        #pragma unroll
        for (int k = 0; k < CPT; ++k) {
            y0[k] = (pm[k] - muM) * rM * g0[k] + be0[k];
            y1[k] = dcs[k] * rA * g1[k] + be1[k];
            y2[k] = dcs[k] * rS * g2[k] + be2[k];
        }

        const size_t row = (size_t)(n * Ll + t);
        float* orow = o1 + row * OUTC;
        __builtin_nontemporal_store(y0, reinterpret_cast<f4*>(orow + c4));
        __builtin_nontemporal_store(y1, reinterpret_cast<f4*>(orow + Cc + c4));
        __builtin_nontemporal_store(y2, reinterpret_cast<f4*>(orow + 2 * Cc + c4));
        if (lane < H2d / CPT)
            __builtin_nontemporal_store(dvf, reinterpret_cast<f4*>(orow + 3 * Cc + lane * CPT));
        __builtin_nontemporal_store(pidxf, reinterpret_cast<f4*>(o2 + row * Cc + c4));
        __builtin_nontemporal_store(pm,    reinterpret_cast<f4*>(o3 + row * Cc + c4));

        v = vn;
    }
}

// ---------------------------------------------------------------------------
extern "C" void kernel_launch(void* const* d_in, const int* in_sizes, int n_in,
                              void* d_out, int out_size, void* d_ws, size_t ws_size,
                              hipStream_t stream)
{
    const float* dem = (const float*)d_in[0];   // (32, 8)
    const float* x   = (const float*)d_in[1];   // (32, 2048, 256)
    const float* lng = (const float*)d_in[2];   // (3, 256)
    const float* lnb = (const float*)d_in[3];   // (3, 256)
    const float* w1  = (const float*)d_in[4];   // (8, 40)
    const float* b1  = (const float*)d_in[5];   // (40,)
    const float* w2  = (const float*)d_in[6];   // (40, 20)
    const float* b2  = (const float*)d_in[7];   // (20,)

    float* out = (float*)d_out;
    float* o1 = out;                                  // (N, L, 788)
    float* o2 = o1 + (size_t)Nn * Ll * OUTC;          // p_max_ind (as float values)
    float* o3 = o2 + (size_t)Nn * Ll * Cc;            // p_max

    // workspace: chunk aggregates
    const size_t nAgg = (size_t)Nn * CHUNKS * Cc;     // 524288
    float* aggM = (float*)d_ws;
    int*   aggI = (int*)(aggM + nAgg);
    float* aggS = (float*)(aggI + nAgg);

    chunk_agg_kernel<<<dim3(Nn * CHUNKS), dim3(TPB), 0, stream>>>(x, aggM, aggI, aggS);
    pool_ln_kernel<<<dim3(Nn * CHUNKS), dim3(TPB), 0, stream>>>(
        x, dem, lng, lnb, w1, b1, w2, b2, aggM, aggI, aggS, o1, o2, o3);
}